// Round 2
// baseline (536.691 us; speedup 1.0000x reference)
//
#include <hip/hip_runtime.h>
#include <hip/hip_bf16.h>
#include <cstdint>

// Problem constants
#define L_SEQ 1024
#define DSRC 512

// ---------------- fp64-accumulate tiled GEMM, C = A (MxK) * B^T (NxK) ----------------
// All row strides are 1024 fp32 elements. 64x64 tile, BK=16, 256 threads,
// each thread computes a 4x4 output patch with f64 FMA (precision: need score
// error < ~3e-6 so top-8 indices match the fp32/fp64 numpy reference; bf16
// (R0) gave 0.479 absmax from top-k boundary flips).
// mode 0: projections. z in {0,1}: A = query/key_t fp32, B = wq/wk fp32,
//         C = qp/kp fp32 (adjacent, stride 2097152 floats), + bias.
// mode 1: scores. z = b*8+v: A = qp + b*1048576 + v*128, B = kp + same,
//         C = f32 scores + z*1048576.
__global__ __launch_bounds__(256) void gemm_f64(const float* __restrict__ A0,
                                                const float* __restrict__ A1,
                                                const float* __restrict__ B0,
                                                const float* __restrict__ B1,
                                                float* __restrict__ C,
                                                const float* __restrict__ bias0,
                                                const float* __restrict__ bias1,
                                                int K, int mode) {
  __shared__ float As[16][64];   // [kk][row]
  __shared__ float Bs[16][64];

  int z = blockIdx.z;
  const float* A;
  const float* B;
  const float* bias = nullptr;
  long coff;
  if (mode == 0) {
    A = (z == 0) ? A0 : A1;
    B = (z == 0) ? B0 : B1;
    bias = (z == 0) ? bias0 : bias1;
    coff = 2097152L * z;
  } else {
    int b = z >> 3, v = z & 7;
    A = A0 + 1048576L * b + 128L * v;
    B = B0 + 1048576L * b + 128L * v;
    coff = 1048576L * z;
  }
  const float* Ab = A + (long)blockIdx.y * 64 * 1024;
  const float* Bb = B + (long)blockIdx.x * 64 * 1024;

  int tid = threadIdx.x;
  int tr = tid >> 4;         // 0..15 -> output rows tr*4..tr*4+3
  int tc = tid & 15;         // 0..15 -> output cols tc*4..tc*4+3

  // staging indices: thread loads one float4 of A and one of B per k-step
  int arow = tid >> 2;           // 0..63
  int kq = (tid & 3) << 2;       // 0,4,8,12

  double acc[4][4];
#pragma unroll
  for (int i = 0; i < 4; i++)
#pragma unroll
    for (int j = 0; j < 4; j++) acc[i][j] = 0.0;

  for (int k0 = 0; k0 < K; k0 += 16) {
    float4 av = *(const float4*)(Ab + (long)arow * 1024 + k0 + kq);
    float4 bv = *(const float4*)(Bb + (long)arow * 1024 + k0 + kq);
    __syncthreads();
    As[kq + 0][arow] = av.x; As[kq + 1][arow] = av.y;
    As[kq + 2][arow] = av.z; As[kq + 3][arow] = av.w;
    Bs[kq + 0][arow] = bv.x; Bs[kq + 1][arow] = bv.y;
    Bs[kq + 2][arow] = bv.z; Bs[kq + 3][arow] = bv.w;
    __syncthreads();

#pragma unroll
    for (int kk = 0; kk < 16; kk++) {
      float4 a = *(const float4*)&As[kk][tr * 4];
      float4 b = *(const float4*)&Bs[kk][tc * 4];
      double ad[4] = {(double)a.x, (double)a.y, (double)a.z, (double)a.w};
      double bd[4] = {(double)b.x, (double)b.y, (double)b.z, (double)b.w};
#pragma unroll
      for (int i = 0; i < 4; i++)
#pragma unroll
        for (int j = 0; j < 4; j++)
          acc[i][j] += ad[i] * bd[j];
    }
  }

  float* Cb = C + coff;
#pragma unroll
  for (int i = 0; i < 4; i++) {
    int row = blockIdx.y * 64 + tr * 4 + i;
    float4 o;
    float* op = &o.x;
#pragma unroll
    for (int j = 0; j < 4; j++) {
      int col = blockIdx.x * 64 + tc * 4 + j;
      double v = acc[i][j];
      if (bias) v += (double)bias[col];
      op[j] = (float)v;
    }
    *(float4*)(Cb + (long)row * 1024 + blockIdx.x * 64 + tc * 4) = o;
  }
}

// ---------------- top-8 + softmax, one wave per q-row ----------------
__global__ __launch_bounds__(256) void topk_softmax_k(const float* __restrict__ scores,
                                                      float* __restrict__ wts,
                                                      int* __restrict__ idxs) {
  int row = blockIdx.x * 4 + (threadIdx.x >> 6);
  int lane = threadIdx.x & 63;
  const float* s = scores + (long)row * 1024;
  float v[16];
#pragma unroll
  for (int i = 0; i < 16; i++) v[i] = s[lane + i * 64];

  float topv[8]; int topi[8];
  for (int t = 0; t < 8; t++) {
    float bv = -1e30f; int bi = 1 << 30; int bslot = -1;
#pragma unroll
    for (int i = 0; i < 16; i++) {
      int ci = lane + i * 64;
      if (v[i] > bv) { bv = v[i]; bi = ci; bslot = i; }
    }
    float rv = bv; int ri = bi;
    for (int off = 32; off; off >>= 1) {
      float ov = __shfl_down(rv, off);
      int oi = __shfl_down(ri, off);
      if (ov > rv || (ov == rv && oi < ri)) { rv = ov; ri = oi; }
    }
    rv = __shfl(rv, 0); ri = __shfl(ri, 0);
    topv[t] = rv; topi[t] = ri;
    if (bslot >= 0 && bi == ri) v[bslot] = -1e30f;  // winner lane removes it
  }
  float m = topv[0], sum = 0.f, e[8];
#pragma unroll
  for (int t = 0; t < 8; t++) { e[t] = __expf(topv[t] - m); sum += e[t]; }
  float inv = 1.0f / sum;
  if (lane < 8) {
    wts[(long)row * 8 + lane] = e[lane] * inv;
    idxs[(long)row * 8 + lane] = topi[lane];
  }
}

// ---------------- gather + weighted sum ----------------
// out[b,v,q,w,d] = sum_k wt[k] * source[b, idx_k + w - 1, d]   (zero OOB)
__global__ __launch_bounds__(256) void gather_out_k(const float* __restrict__ src,
                                                    const float* __restrict__ wts,
                                                    const int* __restrict__ idxs,
                                                    float* __restrict__ out) {
  int rowid = blockIdx.x;
  int b = rowid >> 13;
  int tid = threadIdx.x;
  int d4 = tid & 127;
  int w0 = (tid >> 7) << 1;
  const float4* s4 = (const float4*)src + (long)b * (L_SEQ * (DSRC / 4));
  float wt[8]; int id[8];
#pragma unroll
  for (int k = 0; k < 8; k++) {
    wt[k] = wts[(long)rowid * 8 + k];
    id[k] = idxs[(long)rowid * 8 + k];
  }
  float ax = 0, ay = 0, az = 0, aw = 0;
  float bx = 0, by = 0, bz2 = 0, bw = 0;
#pragma unroll
  for (int k = 0; k < 8; k++) {
    int r0 = id[k] + w0 - 1;
    if ((unsigned)r0 < (unsigned)L_SEQ) {
      float4 x = s4[(long)r0 * 128 + d4];
      ax += wt[k] * x.x; ay += wt[k] * x.y; az += wt[k] * x.z; aw += wt[k] * x.w;
    }
    int r1 = r0 + 1;
    if ((unsigned)r1 < (unsigned)L_SEQ) {
      float4 x = s4[(long)r1 * 128 + d4];
      bx += wt[k] * x.x; by += wt[k] * x.y; bz2 += wt[k] * x.z; bw += wt[k] * x.w;
    }
  }
  float4* o4 = (float4*)out + ((long)rowid * 4 + w0) * 128 + d4;
  o4[0] = make_float4(ax, ay, az, aw);
  o4[128] = make_float4(bx, by, bz2, bw);
}

extern "C" void kernel_launch(void* const* d_in, const int* in_sizes, int n_in,
                              void* d_out, int out_size, void* d_ws, size_t ws_size,
                              hipStream_t stream) {
  (void)in_sizes; (void)n_in; (void)out_size; (void)ws_size;
  const float* query  = (const float*)d_in[0];
  const float* key_t  = (const float*)d_in[1];
  const float* source = (const float*)d_in[2];
  const float* wq     = (const float*)d_in[3];
  const float* bq     = (const float*)d_in[4];
  const float* wk     = (const float*)d_in[5];
  const float* bk     = (const float*)d_in[6];

  char* ws = (char*)d_ws;
  // ws layout (bytes):
  //   0     qp fp32 (2048x1024)  8 MB
  //   8 MB  kp fp32 (2048x1024)  8 MB
  //   16 MB scores fp32 (16x1024x1024) 64 MB
  //   80 MB weights fp32 (16384x8) 512 KB
  //   80.5  indices i32 (16384x8)  512 KB
  float* qp   = (float*)(ws + 0);
  float* kp   = (float*)(ws + 8388608);
  float* sc   = (float*)(ws + 16777216);
  float* wts  = (float*)(ws + 83886080);
  int*   idxs = (int*)(ws + 84410368);

  // projections: C(2048x1024) = X(2048x1024) * W^T(1024x1024) + b, z in {0,1}
  gemm_f64<<<dim3(16, 32, 2), 256, 0, stream>>>(query, key_t, wq, wk, qp, bq, bk, 1024, 0);
  // scores: 16 batches of (1024x1024) = qp_v (1024x128) * kp_v^T
  gemm_f64<<<dim3(16, 16, 16), 256, 0, stream>>>(qp, nullptr, kp, nullptr, sc,
                                                 nullptr, nullptr, 128, 1);

  topk_softmax_k<<<4096, 256, 0, stream>>>(sc, wts, idxs);
  gather_out_k<<<16384, 256, 0, stream>>>(source, wts, idxs, (float*)d_out);
}

// Round 3
// 325.845 us; speedup vs baseline: 1.6471x; 1.6471x over previous
//
#include <hip/hip_runtime.h>
#include <cstdint>

#define L_SEQ 1024
#define DSRC 512
#define XPL 2097152L   // x/proj plane stride (elems) = 2048*1024
#define WPL 1048576L   // weight plane stride = 1024*1024

typedef __attribute__((ext_vector_type(8))) short short8;
typedef __attribute__((ext_vector_type(4))) float floatx4;

__device__ __forceinline__ unsigned short f2bf(float f) {
  unsigned int x = __float_as_uint(f);
  x += 0x7fff + ((x >> 16) & 1);   // RNE
  return (unsigned short)(x >> 16);
}
__device__ __forceinline__ float bf2f(unsigned short h) {
  return __uint_as_float((unsigned)h << 16);
}
// 3-way bf16 split: f = h0 + h1 + h2 + O(2^-27 |f|)
__device__ __forceinline__ void split3(float f, unsigned short* h) {
  h[0] = f2bf(f);
  float d = f - bf2f(h[0]);
  h[1] = f2bf(d);
  h[2] = f2bf(d - bf2f(h[1]));
}

// ---------------- split the 4 fp32 inputs into 3 bf16 planes each ----------------
__global__ __launch_bounds__(256) void split_inputs_k(
    const float* __restrict__ query, const float* __restrict__ key_t,
    const float* __restrict__ wq, const float* __restrict__ wk,
    ushort* __restrict__ xs, ushort* __restrict__ wsp) {
  int blk = blockIdx.x;
  const float* in; ushort* out; long pl; int idx;
  if (blk < 2048)      { in = query; out = xs;           pl = XPL; idx = blk; }
  else if (blk < 4096) { in = key_t; out = xs + 3 * XPL; pl = XPL; idx = blk - 2048; }
  else if (blk < 5120) { in = wq;    out = wsp;          pl = WPL; idx = blk - 4096; }
  else                 { in = wk;    out = wsp + 3 * WPL; pl = WPL; idx = blk - 5120; }
  long e = (long)idx * 1024 + threadIdx.x * 4;
  float4 v = *(const float4*)(in + e);
  unsigned short h0[3], h1[3], h2[3], h3[3];
  split3(v.x, h0); split3(v.y, h1); split3(v.z, h2); split3(v.w, h3);
#pragma unroll
  for (int s = 0; s < 3; s++) {
    ushort4 u; u.x = h0[s]; u.y = h1[s]; u.z = h2[s]; u.w = h3[s];
    *(ushort4*)(out + s * pl + e) = u;
  }
}

// ---------------- projection GEMM: C = X * W^T + bias, bf16x6 emulated fp32 ----------------
// 512 threads = 8 waves (2x4 over 128x128 tile), BK=32. z=0: q, z=1: k.
__global__ __launch_bounds__(512) void proj_gemm_k(
    const ushort* __restrict__ xs, const ushort* __restrict__ wsp,
    float* __restrict__ C, const float* __restrict__ bq, const float* __restrict__ bk) {
  __shared__ ushort As[3][4096];   // [plane][row*32+col]
  __shared__ ushort Bs[3][4096];
  int z = blockIdx.z;
  const ushort* Ab = xs + (long)z * 3 * XPL + (long)blockIdx.y * 128 * 1024;
  const ushort* Bb = wsp + (long)z * 3 * WPL + (long)blockIdx.x * 128 * 1024;
  const float* bias = z ? bk : bq;

  int tid = threadIdx.x;
  int lane = tid & 63, wv = tid >> 6;     // 8 waves
  int wm = wv >> 2, wn = wv & 3;          // wave tile: 64 rows x 32 cols
  int quad = lane >> 4, l16 = lane & 15;

  // staging: 512 threads cover 512 16B-vectors per (plane,tile)
  int sr = tid >> 2;          // row 0..127
  int sc = (tid & 3) * 8;     // col 0/8/16/24

  floatx4 acc[4][2] = {};

  for (int k0 = 0; k0 < 1024; k0 += 32) {
    short8 ga[3], gb[3];
#pragma unroll
    for (int s = 0; s < 3; s++) {
      ga[s] = *(const short8*)(Ab + s * XPL + (long)sr * 1024 + k0 + sc);
      gb[s] = *(const short8*)(Bb + s * WPL + (long)sr * 1024 + k0 + sc);
    }
    __syncthreads();
#pragma unroll
    for (int s = 0; s < 3; s++) {
      *(short8*)(&As[s][sr * 32 + sc]) = ga[s];
      *(short8*)(&Bs[s][sr * 32 + sc]) = gb[s];
    }
    __syncthreads();

    short8 af[3][4];
#pragma unroll
    for (int s = 0; s < 3; s++)
#pragma unroll
      for (int i = 0; i < 4; i++)
        af[s][i] = *(const short8*)(&As[s][(wm * 64 + i * 16 + l16) * 32 + quad * 8]);
#pragma unroll
    for (int j = 0; j < 2; j++) {
      int boff = (wn * 32 + j * 16 + l16) * 32 + quad * 8;
      short8 b0 = *(const short8*)(&Bs[0][boff]);
      short8 b1 = *(const short8*)(&Bs[1][boff]);
      short8 b2 = *(const short8*)(&Bs[2][boff]);
#pragma unroll
      for (int i = 0; i < 4; i++) {
        // small -> large accumulation
        acc[i][j] = __builtin_amdgcn_mfma_f32_16x16x32_bf16(af[1][i], b1, acc[i][j], 0, 0, 0);
        acc[i][j] = __builtin_amdgcn_mfma_f32_16x16x32_bf16(af[0][i], b2, acc[i][j], 0, 0, 0);
        acc[i][j] = __builtin_amdgcn_mfma_f32_16x16x32_bf16(af[2][i], b0, acc[i][j], 0, 0, 0);
        acc[i][j] = __builtin_amdgcn_mfma_f32_16x16x32_bf16(af[0][i], b1, acc[i][j], 0, 0, 0);
        acc[i][j] = __builtin_amdgcn_mfma_f32_16x16x32_bf16(af[1][i], b0, acc[i][j], 0, 0, 0);
        acc[i][j] = __builtin_amdgcn_mfma_f32_16x16x32_bf16(af[0][i], b0, acc[i][j], 0, 0, 0);
      }
    }
  }

  float* Cb = C + (long)z * XPL;
#pragma unroll
  for (int j = 0; j < 2; j++) {
    int col = blockIdx.x * 128 + wn * 32 + j * 16 + l16;
    float bv = bias[col];
#pragma unroll
    for (int i = 0; i < 4; i++) {
#pragma unroll
      for (int r = 0; r < 4; r++) {
        int row = blockIdx.y * 128 + wm * 64 + i * 16 + quad * 4 + r;
        Cb[(long)row * 1024 + col] = acc[i][j][r] + bv;
      }
    }
  }
}

// ---------------- score GEMM: S[z] = qp_v * kp_v^T, on-the-fly bf16x6 split ----------------
// 256 threads = 4 waves (2x2 over 128x128 tile), K=128, BK=32.
__global__ __launch_bounds__(256) void score_gemm_k(
    const float* __restrict__ qp, const float* __restrict__ kp,
    float* __restrict__ S) {
  __shared__ ushort As[3][4096];
  __shared__ ushort Bs[3][4096];
  int z = blockIdx.z;
  int b = z >> 3, v = z & 7;
  const float* Aq = qp + (long)b * 1048576 + v * 128 + (long)blockIdx.y * 128 * 1024;
  const float* Bq = kp + (long)b * 1048576 + v * 128 + (long)blockIdx.x * 128 * 1024;

  int tid = threadIdx.x;
  int lane = tid & 63, wv = tid >> 6;
  int wm = wv >> 1, wn = wv & 1;
  int quad = lane >> 4, l16 = lane & 15;

  int sr = tid >> 3;          // 0..31, rows sr + 32*it
  int sc4 = (tid & 7) * 4;    // float col offset

  floatx4 acc[4][4] = {};

  for (int k0 = 0; k0 < 128; k0 += 32) {
    float4 av[4], bv4[4];
#pragma unroll
    for (int it = 0; it < 4; it++) {
      av[it] = *(const float4*)(Aq + (long)(sr + 32 * it) * 1024 + k0 + sc4);
      bv4[it] = *(const float4*)(Bq + (long)(sr + 32 * it) * 1024 + k0 + sc4);
    }
    __syncthreads();
#pragma unroll
    for (int it = 0; it < 4; it++) {
      int r = sr + 32 * it;
      const float* afp = (const float*)&av[it];
      const float* bfp = (const float*)&bv4[it];
      unsigned short ha[4][3], hb[4][3];
#pragma unroll
      for (int e = 0; e < 4; e++) { split3(afp[e], ha[e]); split3(bfp[e], hb[e]); }
#pragma unroll
      for (int s = 0; s < 3; s++) {
        ushort4 ua; ua.x = ha[0][s]; ua.y = ha[1][s]; ua.z = ha[2][s]; ua.w = ha[3][s];
        ushort4 ub; ub.x = hb[0][s]; ub.y = hb[1][s]; ub.z = hb[2][s]; ub.w = hb[3][s];
        *(ushort4*)(&As[s][r * 32 + sc4]) = ua;
        *(ushort4*)(&Bs[s][r * 32 + sc4]) = ub;
      }
    }
    __syncthreads();

    short8 af[3][4];
#pragma unroll
    for (int s = 0; s < 3; s++)
#pragma unroll
      for (int i = 0; i < 4; i++)
        af[s][i] = *(const short8*)(&As[s][(wm * 64 + i * 16 + l16) * 32 + quad * 8]);
#pragma unroll
    for (int j = 0; j < 4; j++) {
      int boff = (wn * 64 + j * 16 + l16) * 32 + quad * 8;
      short8 b0 = *(const short8*)(&Bs[0][boff]);
      short8 b1 = *(const short8*)(&Bs[1][boff]);
      short8 b2 = *(const short8*)(&Bs[2][boff]);
#pragma unroll
      for (int i = 0; i < 4; i++) {
        acc[i][j] = __builtin_amdgcn_mfma_f32_16x16x32_bf16(af[1][i], b1, acc[i][j], 0, 0, 0);
        acc[i][j] = __builtin_amdgcn_mfma_f32_16x16x32_bf16(af[0][i], b2, acc[i][j], 0, 0, 0);
        acc[i][j] = __builtin_amdgcn_mfma_f32_16x16x32_bf16(af[2][i], b0, acc[i][j], 0, 0, 0);
        acc[i][j] = __builtin_amdgcn_mfma_f32_16x16x32_bf16(af[0][i], b1, acc[i][j], 0, 0, 0);
        acc[i][j] = __builtin_amdgcn_mfma_f32_16x16x32_bf16(af[1][i], b0, acc[i][j], 0, 0, 0);
        acc[i][j] = __builtin_amdgcn_mfma_f32_16x16x32_bf16(af[0][i], b0, acc[i][j], 0, 0, 0);
      }
    }
  }

  float* Sb = S + (long)z * 1048576;
#pragma unroll
  for (int j = 0; j < 4; j++) {
    int col = blockIdx.x * 128 + wn * 64 + j * 16 + l16;
#pragma unroll
    for (int i = 0; i < 4; i++) {
#pragma unroll
      for (int r = 0; r < 4; r++) {
        int row = blockIdx.y * 128 + wm * 64 + i * 16 + quad * 4 + r;
        Sb[(long)row * 1024 + col] = acc[i][j][r];
      }
    }
  }
}

// ---------------- top-8 + softmax, one wave per q-row ----------------
__global__ __launch_bounds__(256) void topk_softmax_k(const float* __restrict__ scores,
                                                      float* __restrict__ wts,
                                                      int* __restrict__ idxs) {
  int row = blockIdx.x * 4 + (threadIdx.x >> 6);
  int lane = threadIdx.x & 63;
  const float* s = scores + (long)row * 1024;
  float v[16];
#pragma unroll
  for (int i = 0; i < 16; i++) v[i] = s[lane + i * 64];

  float topv[8]; int topi[8];
  for (int t = 0; t < 8; t++) {
    float bv = -1e30f; int bi = 1 << 30; int bslot = -1;
#pragma unroll
    for (int i = 0; i < 16; i++) {
      int ci = lane + i * 64;
      if (v[i] > bv) { bv = v[i]; bi = ci; bslot = i; }
    }
    float rv = bv; int ri = bi;
    for (int off = 32; off; off >>= 1) {
      float ov = __shfl_down(rv, off);
      int oi = __shfl_down(ri, off);
      if (ov > rv || (ov == rv && oi < ri)) { rv = ov; ri = oi; }
    }
    rv = __shfl(rv, 0); ri = __shfl(ri, 0);
    topv[t] = rv; topi[t] = ri;
    if (bslot >= 0 && bi == ri) v[bslot] = -1e30f;
  }
  float m = topv[0], sum = 0.f, e[8];
#pragma unroll
  for (int t = 0; t < 8; t++) { e[t] = __expf(topv[t] - m); sum += e[t]; }
  float inv = 1.0f / sum;
  if (lane < 8) {
    wts[(long)row * 8 + lane] = e[lane] * inv;
    idxs[(long)row * 8 + lane] = topi[lane];
  }
}

// ---------------- gather + weighted sum ----------------
__global__ __launch_bounds__(256) void gather_out_k(const float* __restrict__ src,
                                                    const float* __restrict__ wts,
                                                    const int* __restrict__ idxs,
                                                    float* __restrict__ out) {
  int rowid = blockIdx.x;
  int b = rowid >> 13;
  int tid = threadIdx.x;
  int d4 = tid & 127;
  int w0 = (tid >> 7) << 1;
  const float4* s4 = (const float4*)src + (long)b * (L_SEQ * (DSRC / 4));
  float wt[8]; int id[8];
#pragma unroll
  for (int k = 0; k < 8; k++) {
    wt[k] = wts[(long)rowid * 8 + k];
    id[k] = idxs[(long)rowid * 8 + k];
  }
  float ax = 0, ay = 0, az = 0, aw = 0;
  float bx = 0, by = 0, bz2 = 0, bw = 0;
#pragma unroll
  for (int k = 0; k < 8; k++) {
    int r0 = id[k] + w0 - 1;
    if ((unsigned)r0 < (unsigned)L_SEQ) {
      float4 x = s4[(long)r0 * 128 + d4];
      ax += wt[k] * x.x; ay += wt[k] * x.y; az += wt[k] * x.z; aw += wt[k] * x.w;
    }
    int r1 = r0 + 1;
    if ((unsigned)r1 < (unsigned)L_SEQ) {
      float4 x = s4[(long)r1 * 128 + d4];
      bx += wt[k] * x.x; by += wt[k] * x.y; bz2 += wt[k] * x.z; bw += wt[k] * x.w;
    }
  }
  float4* o4 = (float4*)out + ((long)rowid * 4 + w0) * 128 + d4;
  o4[0] = make_float4(ax, ay, az, aw);
  o4[128] = make_float4(bx, by, bz2, bw);
}

extern "C" void kernel_launch(void* const* d_in, const int* in_sizes, int n_in,
                              void* d_out, int out_size, void* d_ws, size_t ws_size,
                              hipStream_t stream) {
  (void)in_sizes; (void)n_in; (void)out_size; (void)ws_size;
  const float* query  = (const float*)d_in[0];
  const float* key_t  = (const float*)d_in[1];
  const float* source = (const float*)d_in[2];
  const float* wq     = (const float*)d_in[3];
  const float* bq     = (const float*)d_in[4];
  const float* wk     = (const float*)d_in[5];
  const float* bk     = (const float*)d_in[6];

  char* ws = (char*)d_ws;
  // ws layout (bytes), total 84,934,656 (== R1's proven footprint):
  //   0         qp fp32 (2048x1024)             8 MB   live: proj -> score
  //   8388608   kp fp32                         8 MB
  //   16777216  wts fp32 (16384x8)              512 KB
  //   17301504  idxs i32                        512 KB
  //   17825792  xs: 6 bf16 planes (xq,xk)       24 MB  dead after proj
  //   43008000~ wsp: 6 bf16 planes (wq,wk)      12 MB  dead after proj
  //   17825792  scores fp32 (16x1024x1024)      64 MB  (reuses xs/wsp region)
  float* qp   = (float*)(ws + 0);
  float* kp   = (float*)(ws + 8388608);
  float* wts  = (float*)(ws + 16777216);
  int*   idxs = (int*)(ws + 17301504);
  ushort* xs  = (ushort*)(ws + 17825792);
  ushort* wsp = (ushort*)(ws + 17825792 + 25165824);
  float* sc   = (float*)(ws + 17825792);

  split_inputs_k<<<6144, 256, 0, stream>>>(query, key_t, wq, wk, xs, wsp);
  proj_gemm_k<<<dim3(8, 16, 2), 512, 0, stream>>>(xs, wsp, qp, bq, bk);
  score_gemm_k<<<dim3(8, 8, 16), 256, 0, stream>>>(qp, kp, sc);
  topk_softmax_k<<<4096, 256, 0, stream>>>(sc, wts, idxs);
  gather_out_k<<<16384, 256, 0, stream>>>(source, wts, idxs, (float*)d_out);
}